// Round 5
// baseline (3482.401 us; speedup 1.0000x reference)
//
#include <hip/hip_runtime.h>
#include <math.h>

#define CTX    2048
#define DM     1024
#define VOCAB  32000
#define BATCH  4
#define NROWS  (BATCH * CTX)      // 8192
#define SCALE  0.03125f           // 1024^-0.5

typedef float        f32x4 __attribute__((ext_vector_type(4)));
typedef short        s16x8 __attribute__((ext_vector_type(8)));
typedef unsigned int u32x2 __attribute__((ext_vector_type(2)));

// ---- async global -> LDS, 16B per lane (m97: width=16 is the big lever) ----
__device__ __forceinline__ void gload16(const unsigned short* g, unsigned short* l) {
    __builtin_amdgcn_global_load_lds(
        (const __attribute__((address_space(1))) unsigned int*)g,
        (__attribute__((address_space(3))) unsigned int*)l, 16, 0, 0);
}

// ---- fp32 -> split bf16 (hi + lo), RNE ------------------------------------
__device__ __forceinline__ unsigned short bf16_hi(float x) {
    unsigned int u = __float_as_uint(x);
    return (unsigned short)((u + 0x7FFFu + ((u >> 16) & 1u)) >> 16);
}
__device__ __forceinline__ float bf16_f(unsigned short b) {
    return __uint_as_float(((unsigned int)b) << 16);
}
__device__ __forceinline__ void split_bf16(float x, unsigned short& h, unsigned short& l) {
    h = bf16_hi(x);
    l = bf16_hi(x - bf16_f(h));
}

// ---------------------------------------------------------------------------
// transpose_split: W fp32 [R][C]  ->  Wt_hi/Wt_lo bf16 [C][R]
// grid (R/32, C/32), 256 threads, 32x32 LDS tile
// ---------------------------------------------------------------------------
__global__ __launch_bounds__(256) void transpose_split(const float* __restrict__ W,
                                                       unsigned short* __restrict__ Th,
                                                       unsigned short* __restrict__ Tl,
                                                       int R, int C) {
    __shared__ float tile[32][33];
    int r0 = blockIdx.x * 32, c0 = blockIdx.y * 32;
    int tid = threadIdx.x;
    {
        int tr = tid >> 3, tc = (tid & 7) * 4;
        float4 v = *(const float4*)(W + (size_t)(r0 + tr) * C + c0 + tc);
        tile[tr][tc + 0] = v.x; tile[tr][tc + 1] = v.y;
        tile[tr][tc + 2] = v.z; tile[tr][tc + 3] = v.w;
    }
    __syncthreads();
    {
        int oc = tid >> 3, orr = (tid & 7) * 4;
        unsigned short h[4], l[4];
#pragma unroll
        for (int q = 0; q < 4; q++) split_bf16(tile[orr + q][oc], h[q], l[q]);
        size_t o = (size_t)(c0 + oc) * R + r0 + orr;
        u32x2 ph, pl;
        ph[0] = (unsigned int)h[0] | ((unsigned int)h[1] << 16);
        ph[1] = (unsigned int)h[2] | ((unsigned int)h[3] << 16);
        pl[0] = (unsigned int)l[0] | ((unsigned int)l[1] << 16);
        pl[1] = (unsigned int)l[2] | ((unsigned int)l[3] << 16);
        *(u32x2*)(Th + o) = ph;
        *(u32x2*)(Tl + o) = pl;
    }
}

// ---------------------------------------------------------------------------
// embed_split: h = tok_emb[x[row]] + pos_emb[row % CTX], written as bf16 hi/lo
// ---------------------------------------------------------------------------
__global__ __launch_bounds__(256) void embed_split(const int* __restrict__ x,
                                                   const float* __restrict__ tok,
                                                   const float* __restrict__ pos,
                                                   unsigned short* __restrict__ Hh,
                                                   unsigned short* __restrict__ Hl) {
    int row = blockIdx.x;
    int t = row & (CTX - 1);
    int token = x[row];
    int i = threadIdx.x;
    float4 a = *(const float4*)(tok + (size_t)token * DM + 4 * i);
    float4 b = *(const float4*)(pos + (size_t)t * DM + 4 * i);
    float v[4] = {a.x + b.x, a.y + b.y, a.z + b.z, a.w + b.w};
    unsigned short h[4], l[4];
#pragma unroll
    for (int q = 0; q < 4; q++) split_bf16(v[q], h[q], l[q]);
    size_t o = (size_t)row * DM + 4 * i;
    u32x2 ph, pl;
    ph[0] = (unsigned int)h[0] | ((unsigned int)h[1] << 16);
    ph[1] = (unsigned int)h[2] | ((unsigned int)h[3] << 16);
    pl[0] = (unsigned int)l[0] | ((unsigned int)l[1] << 16);
    pl[1] = (unsigned int)l[2] | ((unsigned int)l[3] << 16);
    *(u32x2*)(Hh + o) = ph;
    *(u32x2*)(Hl + o) = pl;
}

// ---------------------------------------------------------------------------
// Split-bf16 MFMA GEMM, NT-everywhere (m97 structure), z-batched:
//   per z: C[M][N] = A[M][K] * B[N][K]^T (+bias); A,B bf16 hi/lo, [rows][K].
//   A*B ~= Ah*Bh + Ah*Bl + Al*Bh  (fp32 accum; lo*lo dropped, ~3e-5 rel err)
//   sA/sB/sC: per-blockIdx.z ELEMENT offsets (0 when grid.z == 1).
// EPI: 0 = fp32 C, 1 = split-bf16 C.  BIAS: 0 none, 1 per-col, 2 per-row.
// CSKIP: skip blocks above causal diagonal.  CKLIM: K limited to (bm+1)*BM.
// SWZ: XCD-aware bijective block swizzle (T1/m192; requires nwg % 8 == 0) —
//      HBM-bound shapes only (LM head); L3-fit shapes skip it (m160).
// 128x128 tile, BK=32, 4 waves (2x2), 64x64/wave, mfma_f32_16x16x32_bf16.
// Staging: global_load_lds dwordx4 into LINEAR [128][32] LDS (m104: dest is
// wave-uniform base + lane*16 — no padding allowed). 2-barrier K-loop.
// All dims are exact multiples of 128/32 here — no edge guards.
// ---------------------------------------------------------------------------
#define BM 128
#define BN 128
#define BK 32

template<int EPI, int BIAS, bool CSKIP, bool CKLIM, bool SWZ>
__global__ __launch_bounds__(256) void gemm_nt(
    const unsigned short* __restrict__ Ah, const unsigned short* __restrict__ Al,
    const unsigned short* __restrict__ Bh, const unsigned short* __restrict__ Bl,
    const float* __restrict__ bias,
    float* __restrict__ Cf, unsigned short* __restrict__ Ch, unsigned short* __restrict__ Cl,
    int M, int N, int K, int lda, int ldb, int ldc,
    size_t sA, size_t sB, size_t sC)
{
    int bm, bn;
    if constexpr (SWZ) {
        // flat id -> XCD-contiguous chunk remap: sid = (f%8)*(nwg/8) + f/8
        int nx = gridDim.x;
        int f = blockIdx.y * nx + blockIdx.x;
        int cpx = (nx * gridDim.y) >> 3;
        int sid = (f & 7) * cpx + (f >> 3);
        bm = sid % nx;
        bn = sid / nx;
    } else {
        bm = blockIdx.x;
        bn = blockIdx.y;
    }
    if (CSKIP && bn > bm) return;

    const size_t zA = (size_t)blockIdx.z * sA;
    const size_t zB = (size_t)blockIdx.z * sB;
    const size_t zC = (size_t)blockIdx.z * sC;

    __shared__ unsigned short As_h[BM * BK], As_l[BM * BK];
    __shared__ unsigned short Bs_h[BN * BK], Bs_l[BN * BK];

    int tid = threadIdx.x;
    int lane = tid & 63, wave = tid >> 6;
    int wr = wave >> 1, wc = wave & 1;      // 2x2 wave grid, 64x64 each
    int frow = lane & 15, kq = lane >> 4;   // fragment row / k-quadrant

    int Keff = K;
    if (CKLIM) { int kl = (bm + 1) * BM; Keff = (kl < K) ? kl : K; }

    f32x4 acc[4][4];
#pragma unroll
    for (int i = 0; i < 4; i++)
#pragma unroll
        for (int j = 0; j < 4; j++) acc[i][j] = (f32x4)0.0f;

    // staging: wave w, call c stages rows [w*32+c*16, +16): 64 lanes x 16B.
    // per-lane global src row = w*32 + c*16 + (lane>>2), k = (lane&3)*8;
    // LDS dest (HW): wave-uniform base + lane*16B == linear [row][k] order
    // ((lane>>2)*32 + (lane&3)*8 == lane*8 ushorts). [m104/m173]
    const int srow = wave * 32 + (lane >> 2);
    const int sk = (lane & 3) * 8;
    const size_t a0 = zA + (size_t)(bm * BM + srow) * lda + sk;
    const size_t a1 = a0 + (size_t)16 * lda;
    const size_t b0 = zB + (size_t)(bn * BN + srow) * ldb + sk;
    const size_t b1 = b0 + (size_t)16 * ldb;
    const int l0 = wave * 1024;         // ushort offset of wave seg, call 0
    const int l1 = wave * 1024 + 512;   // call 1

    for (int k0 = 0; k0 < Keff; k0 += BK) {
        gload16(Ah + a0 + k0, As_h + l0);
        gload16(Ah + a1 + k0, As_h + l1);
        gload16(Al + a0 + k0, As_l + l0);
        gload16(Al + a1 + k0, As_l + l1);
        gload16(Bh + b0 + k0, Bs_h + l0);
        gload16(Bh + b1 + k0, Bs_h + l1);
        gload16(Bl + b0 + k0, Bs_l + l0);
        gload16(Bl + b1 + k0, Bs_l + l1);
        __syncthreads();   // drains vmcnt(0): staged tiles visible

        s16x8 ah[4], al4[4], bh4[4], bl4[4];
#pragma unroll
        for (int i = 0; i < 4; i++) {
            int ra = (wr * 64 + i * 16 + frow) * BK + kq * 8;
            int rb = (wc * 64 + i * 16 + frow) * BK + kq * 8;
            ah[i]  = *(const s16x8*)(As_h + ra);
            al4[i] = *(const s16x8*)(As_l + ra);
            bh4[i] = *(const s16x8*)(Bs_h + rb);
            bl4[i] = *(const s16x8*)(Bs_l + rb);
        }
#pragma unroll
        for (int i = 0; i < 4; i++)
#pragma unroll
            for (int j = 0; j < 4; j++) {
                acc[i][j] = __builtin_amdgcn_mfma_f32_16x16x32_bf16(ah[i],  bh4[j], acc[i][j], 0, 0, 0);
                acc[i][j] = __builtin_amdgcn_mfma_f32_16x16x32_bf16(ah[i],  bl4[j], acc[i][j], 0, 0, 0);
                acc[i][j] = __builtin_amdgcn_mfma_f32_16x16x32_bf16(al4[i], bh4[j], acc[i][j], 0, 0, 0);
            }
        __syncthreads();   // fragment reads done before next staging
    }

    // epilogue: C/D layout col = lane&15, row = (lane>>4)*4 + reg   [m89]
#pragma unroll
    for (int i = 0; i < 4; i++)
#pragma unroll
        for (int j = 0; j < 4; j++) {
            int col = bn * BN + wc * 64 + j * 16 + frow;
#pragma unroll
            for (int r = 0; r < 4; r++) {
                int row = bm * BM + wr * 64 + i * 16 + kq * 4 + r;
                float v = acc[i][j][r];
                if constexpr (BIAS == 1) v += bias[col];
                if constexpr (BIAS == 2) v += bias[row];
                size_t o = zC + (size_t)row * ldc + col;
                if constexpr (EPI == 0) {
                    Cf[o] = v;
                } else {
                    unsigned short h, l;
                    split_bf16(v, h, l);
                    Ch[o] = h;
                    Cl[o] = l;
                }
            }
        }
}

// ---------------------------------------------------------------------------
// softmax_split: causal row t of batch blockIdx.y's [CTX][CTX] fp32 scores ->
// split-bf16 probs (zeros past diagonal). grid (CTX, BATCH), 256 thr (8 cols).
// ---------------------------------------------------------------------------
__global__ __launch_bounds__(256) void softmax_split(const float* __restrict__ scb,
                                                     unsigned short* __restrict__ phb,
                                                     unsigned short* __restrict__ plb) {
    int t = blockIdx.x;
    size_t zoff = (size_t)blockIdx.y * CTX * CTX;
    const float* row = scb + zoff + (size_t)t * CTX;
    unsigned short* ph = phb + zoff;
    unsigned short* pl = plb + zoff;
    int tid = threadIdx.x;
    int lane = tid & 63, wave = tid >> 6;

    float4 u0 = *(const float4*)(row + 4 * tid);
    float4 u1 = *(const float4*)(row + 1024 + 4 * tid);
    float v[8] = {u0.x, u0.y, u0.z, u0.w, u1.x, u1.y, u1.z, u1.w};
    int c[8];
#pragma unroll
    for (int e = 0; e < 4; e++) { c[e] = 4 * tid + e; c[4 + e] = 1024 + 4 * tid + e; }

    float m = -INFINITY;
#pragma unroll
    for (int e = 0; e < 8; e++) if (c[e] <= t) m = fmaxf(m, v[e]);
#pragma unroll
    for (int off = 1; off < 64; off <<= 1) m = fmaxf(m, __shfl_xor(m, off));
    __shared__ float rm[4], rs[4];
    if (lane == 0) rm[wave] = m;
    __syncthreads();
    m = fmaxf(fmaxf(rm[0], rm[1]), fmaxf(rm[2], rm[3]));

    float p[8];
    float s = 0.f;
#pragma unroll
    for (int e = 0; e < 8; e++) {
        p[e] = (c[e] <= t) ? expf((v[e] - m) * SCALE) : 0.f;
        s += p[e];
    }
#pragma unroll
    for (int off = 1; off < 64; off <<= 1) s += __shfl_xor(s, off);
    if (lane == 0) rs[wave] = s;
    __syncthreads();
    s = rs[0] + rs[1] + rs[2] + rs[3];
    float inv = 1.f / s;

    unsigned short h[8], l[8];
#pragma unroll
    for (int e = 0; e < 8; e++) split_bf16(p[e] * inv, h[e], l[e]);
    size_t o0 = (size_t)t * CTX + 4 * tid;
    u32x2 a, b;
    a[0] = (unsigned int)h[0] | ((unsigned int)h[1] << 16);
    a[1] = (unsigned int)h[2] | ((unsigned int)h[3] << 16);
    b[0] = (unsigned int)h[4] | ((unsigned int)h[5] << 16);
    b[1] = (unsigned int)h[6] | ((unsigned int)h[7] << 16);
    *(u32x2*)(ph + o0) = a;
    *(u32x2*)(ph + o0 + 1024) = b;
    a[0] = (unsigned int)l[0] | ((unsigned int)l[1] << 16);
    a[1] = (unsigned int)l[2] | ((unsigned int)l[3] << 16);
    b[0] = (unsigned int)l[4] | ((unsigned int)l[5] << 16);
    b[1] = (unsigned int)l[6] | ((unsigned int)l[7] << 16);
    *(u32x2*)(pl + o0) = a;
    *(u32x2*)(pl + o0 + 1024) = b;
}

// ---------------------------------------------------------------------------
// Per-row online LSE + target logit -> atomic mean accumulation (fp32).
// ---------------------------------------------------------------------------
__global__ __launch_bounds__(256) void loss_kernel(const float* __restrict__ logits,
                                                   const int* __restrict__ target,
                                                   float* __restrict__ accum) {
    int row = blockIdx.x;
    const float* lr = logits + (size_t)row * VOCAB;
    const float4* l4 = (const float4*)lr;
    int tid = threadIdx.x;

    float m = -INFINITY, s = 0.f;
    for (int i = tid; i < VOCAB / 4; i += 256) {
        float4 v = l4[i];
        float mv = fmaxf(fmaxf(v.x, v.y), fmaxf(v.z, v.w));
        if (mv > m) { s *= expf(m - mv); m = mv; }
        s += expf(v.x - m) + expf(v.y - m) + expf(v.z - m) + expf(v.w - m);
    }
#pragma unroll
    for (int off = 1; off < 64; off <<= 1) {
        float m2 = __shfl_xor(m, off);
        float s2 = __shfl_xor(s, off);
        float nm = fmaxf(m, m2);
        s = s * expf(m - nm) + s2 * expf(m2 - nm);
        m = nm;
    }
    __shared__ float rm[4], rs[4];
    if ((tid & 63) == 0) { rm[tid >> 6] = m; rs[tid >> 6] = s; }
    __syncthreads();
    if (tid == 0) {
        float M0 = rm[0], S0 = rs[0];
        for (int w = 1; w < 4; w++) {
            float nm = fmaxf(M0, rm[w]);
            S0 = S0 * expf(M0 - nm) + rs[w] * expf(rm[w] - nm);
            M0 = nm;
        }
        float lse = M0 + logf(S0);
        float tl = lr[target[row]];
        atomicAdd(accum, (lse - tl) * (1.0f / NROWS));
    }
}

__global__ void zero_kernel(float* p) { *p = 0.f; }
__global__ void finalize_kernel(const float* a, float* out) { *out = *a; }

// ---------------------------------------------------------------------------
extern "C" void kernel_launch(void* const* d_in, const int* in_sizes, int n_in,
                              void* d_out, int out_size, void* d_ws, size_t ws_size,
                              hipStream_t stream) {
    const int*   x      = (const int*)d_in[0];
    const int*   target = (const int*)d_in[1];
    const float* tok    = (const float*)d_in[2];
    const float* pos    = (const float*)d_in[3];
    const float* Wq     = (const float*)d_in[4];
    const float* bq     = (const float*)d_in[5];
    const float* Wk     = (const float*)d_in[6];
    const float* bk     = (const float*)d_in[7];
    const float* Wv     = (const float*)d_in[8];
    const float* bv     = (const float*)d_in[9];
    const float* Wlm    = (const float*)d_in[10];
    const float* blm    = (const float*)d_in[11];

    float* logits = (float*)d_out;
    float* loss   = logits + (size_t)NROWS * VOCAB;

    char* cur = (char*)d_ws;
    auto alloc = [&cur](size_t bytes) -> void* {
        void* r = (void*)cur;
        cur += (bytes + 255) & ~(size_t)255;
        return r;
    };
    typedef unsigned short us;
    // --- region0 (224 MB): all dead after attention; Wlt aliases its head ---
    char* region0 = cur;
    us* h_h = (us*)alloc((size_t)NROWS * DM * 2);          // 16 MB
    us* h_l = (us*)alloc((size_t)NROWS * DM * 2);
    us* q_h = (us*)alloc((size_t)NROWS * DM * 2);
    us* q_l = (us*)alloc((size_t)NROWS * DM * 2);
    us* k_h = (us*)alloc((size_t)NROWS * DM * 2);
    us* k_l = (us*)alloc((size_t)NROWS * DM * 2);
    float* sc = (float*)alloc((size_t)BATCH * CTX * CTX * 4);  // 64 MB
    us* p_h = (us*)alloc((size_t)BATCH * CTX * CTX * 2);       // 32 MB
    us* p_l = (us*)alloc((size_t)BATCH * CTX * CTX * 2);       // 32 MB
    // --- live through LM head ---
    us* vT_h = (us*)alloc((size_t)DM * NROWS * 2);
    us* vT_l = (us*)alloc((size_t)DM * NROWS * 2);
    us* y_h  = (us*)alloc((size_t)NROWS * DM * 2);
    us* y_l  = (us*)alloc((size_t)NROWS * DM * 2);
    us* Wqt_h = (us*)alloc((size_t)DM * DM * 2);
    us* Wqt_l = (us*)alloc((size_t)DM * DM * 2);
    us* Wkt_h = (us*)alloc((size_t)DM * DM * 2);
    us* Wkt_l = (us*)alloc((size_t)DM * DM * 2);
    us* Wvt_h = (us*)alloc((size_t)DM * DM * 2);
    us* Wvt_l = (us*)alloc((size_t)DM * DM * 2);
    float* accum = (float*)alloc(256);
    // Wlt (2 x 64 MB = 128 MB) aliases region0 head (h/q/k/sc dead by then)
    us* Wlt_h = (us*)region0;
    us* Wlt_l = Wlt_h + (size_t)VOCAB * DM;

    dim3 blk(256);

    // --- preprocess ---
    transpose_split<<<dim3(DM / 32, DM / 32), blk, 0, stream>>>(Wq, Wqt_h, Wqt_l, DM, DM);
    transpose_split<<<dim3(DM / 32, DM / 32), blk, 0, stream>>>(Wk, Wkt_h, Wkt_l, DM, DM);
    transpose_split<<<dim3(DM / 32, DM / 32), blk, 0, stream>>>(Wv, Wvt_h, Wvt_l, DM, DM);
    embed_split<<<NROWS, blk, 0, stream>>>(x, tok, pos, h_h, h_l);

    // --- QKV projections (NT; weights pre-transposed; L3-fit -> no swizzle) ---
    gemm_nt<1, 1, false, false, false><<<dim3(NROWS / BM, DM / BN), blk, 0, stream>>>(
        h_h, h_l, Wqt_h, Wqt_l, bq, nullptr, q_h, q_l, NROWS, DM, DM, DM, DM, DM, 0, 0, 0);
    gemm_nt<1, 1, false, false, false><<<dim3(NROWS / BM, DM / BN), blk, 0, stream>>>(
        h_h, h_l, Wkt_h, Wkt_l, bk, nullptr, k_h, k_l, NROWS, DM, DM, DM, DM, DM, 0, 0, 0);
    // vT = Wv^T @ h^T (+bv per OUTPUT ROW d): [DM][NROWS], token-contiguous
    gemm_nt<1, 2, false, false, false><<<dim3(DM / BM, NROWS / BN), blk, 0, stream>>>(
        Wvt_h, Wvt_l, h_h, h_l, bv, nullptr, vT_h, vT_l, DM, NROWS, DM, DM, DM, NROWS, 0, 0, 0);

    // --- attention, all batches in one launch via blockIdx.z ---
    // QK^T: per z, sc[z] = q[z] @ k[z]^T  (causal block skip)
    gemm_nt<0, 0, true, false, false><<<dim3(CTX / BM, CTX / BN, BATCH), blk, 0, stream>>>(
        q_h, q_l, k_h, k_l, nullptr, sc, nullptr, nullptr,
        CTX, CTX, DM, DM, DM, CTX,
        (size_t)CTX * DM, (size_t)CTX * DM, (size_t)CTX * CTX);
    softmax_split<<<dim3(CTX, BATCH), blk, 0, stream>>>(sc, p_h, p_l);
    // PV: per z, y[z] = p[z] @ vT[:, z*CTX..]^T  (K limited to causal extent)
    gemm_nt<1, 0, false, true, false><<<dim3(CTX / BM, DM / BN, BATCH), blk, 0, stream>>>(
        p_h, p_l, vT_h, vT_l, nullptr, nullptr, y_h, y_l,
        CTX, DM, CTX, CTX, NROWS, DM,
        (size_t)CTX * CTX, (size_t)CTX, (size_t)CTX * DM);

    // --- LM-head weight transpose (region0 now dead -> Wlt aliases it) ---
    transpose_split<<<dim3(DM / 32, VOCAB / 32), blk, 0, stream>>>(Wlm, Wlt_h, Wlt_l, DM, VOCAB);

    // --- LM head -> fp32 logits in d_out (HBM-bound: XCD swizzle ON, 16000%8==0) ---
    gemm_nt<0, 1, false, false, true><<<dim3(NROWS / BM, VOCAB / BN), blk, 0, stream>>>(
        y_h, y_l, Wlt_h, Wlt_l, blm, logits, nullptr, nullptr,
        NROWS, VOCAB, DM, DM, DM, VOCAB, 0, 0, 0);

    // --- loss ---
    zero_kernel<<<1, 1, 0, stream>>>(accum);
    loss_kernel<<<NROWS, blk, 0, stream>>>(logits, target, accum);
    finalize_kernel<<<1, 1, 0, stream>>>(accum, loss);
}